// Round 1
// baseline (1882.822 us; speedup 1.0000x reference)
//
#include <hip/hip_runtime.h>
#include <math.h>

// Problem dims (fixed by reference setup_inputs)
#define NN   20000   // nodes
#define BG   128     // graphs
#define EE   320000  // edges
#define FIN  768
#define RAWF 5000
#define HD   256
#define NC   4

typedef __attribute__((ext_vector_type(4))) float          f32x4;
typedef __attribute__((ext_vector_type(8))) unsigned short u16x8;
typedef __attribute__((ext_vector_type(4))) unsigned short u16x4;
typedef __attribute__((ext_vector_type(8))) __bf16         bf16x8;

__device__ __forceinline__ unsigned short f2bf(float f) {
  unsigned u = __float_as_uint(f);
  u += 0x7FFFu + ((u >> 16) & 1u);
  return (unsigned short)(u >> 16);
}

static inline int ceil_div(int a, int b) { return (a + b - 1) / b; }

// ---------------------------------------------------------------- CSR build
__global__ void count_deg_k(const int* __restrict__ dst, int* __restrict__ deg, int e) {
  int i = blockIdx.x * 256 + threadIdx.x;
  if (i < e) atomicAdd(&deg[dst[i]], 1);
}

__global__ void dinv_k(const int* __restrict__ deg, float* __restrict__ dinv, int n) {
  int i = blockIdx.x * 256 + threadIdx.x;
  if (i < n) dinv[i] = rsqrtf((float)(deg[i] + 1));  // +1 self loop; always >=1
}

__global__ __launch_bounds__(1024) void scan_k(const int* __restrict__ deg,
                                               int* __restrict__ rowptr,
                                               int* __restrict__ cursor, int n) {
  __shared__ int buf[1024];
  __shared__ int carry_s;
  int t = threadIdx.x;
  if (t == 0) carry_s = 0;
  __syncthreads();
  for (int base = 0; base < n; base += 1024) {
    int i = base + t;
    int v = (i < n) ? deg[i] : 0;
    buf[t] = v;
    __syncthreads();
    int acc = v;
    for (int off = 1; off < 1024; off <<= 1) {
      int other = (t >= off) ? buf[t - off] : 0;
      __syncthreads();
      acc += other;
      buf[t] = acc;
      __syncthreads();
    }
    int carry = carry_s;
    if (i < n) { int excl = carry + acc - v; rowptr[i] = excl; cursor[i] = excl; }
    __syncthreads();               // all reads of carry_s done
    if (t == 0) carry_s = carry + buf[1023];
    __syncthreads();
  }
  if (t == 0) rowptr[n] = carry_s;
}

__global__ void scatter_k(const int* __restrict__ src, const int* __restrict__ dst,
                          int* __restrict__ cursor, int* __restrict__ col, int e) {
  int i = blockIdx.x * 256 + threadIdx.x;
  if (i < e) {
    int d = dst[i];
    int p = atomicAdd(&cursor[d], 1);
    col[p] = src[i];
  }
}

__global__ void segbounds_k(const int* __restrict__ batch, int* __restrict__ s,
                            int* __restrict__ e, int n) {
  int i = blockIdx.x * 256 + threadIdx.x;
  if (i >= n) return;
  int b = batch[i];
  if (i == 0 || batch[i - 1] != b) s[b] = i;
  if (i == n - 1 || batch[i + 1] != b) e[b] = i + 1;
}

// ------------------------------------------------- weight transpose+convert
// in [K][N] fp32 -> out [N][K] bf16
__global__ void transpose_cvt_k(const float* __restrict__ in, unsigned short* __restrict__ out,
                                int K, int N) {
  int k = blockIdx.x * 256 + threadIdx.x;
  int n = blockIdx.y;
  if (k < K) out[(size_t)n * K + k] = f2bf(in[(size_t)k * N + n]);
}

// ------------------------------------------------------------- MFMA GEMM
// C[M][N] (+)= A[M][K] fp32 @ Bt[N][K] bf16, tiles 128x128x32, 256 thr = 4 waves
__global__ __launch_bounds__(256) void gemm_bf16_k(
    const float* __restrict__ A, const unsigned short* __restrict__ Bt,
    float* __restrict__ C, int M, int N, int K, int kchunk, int atomic_out) {
  __shared__ unsigned short As[128 * 40];  // pad 32->40: 2-way bank alias only
  __shared__ unsigned short Bs[128 * 40];
  int tid = threadIdx.x;
  int lane = tid & 63, wave = tid >> 6;
  int quad = lane >> 4, l16 = lane & 15;
  int koff = quad * 8;
  int bn = blockIdx.x * 128;   // N-tile fastest -> paired M-tiles share A in cache
  int bm = blockIdx.y * 128;
  int wm = (wave >> 1) * 64, wn = (wave & 1) * 64;
  int kbegin = blockIdx.z * kchunk;
  int kend = kbegin + kchunk; if (kend > K) kend = K;

  f32x4 acc[4][4] = {};

  for (int k0 = kbegin; k0 < kend; k0 += 32) {
    // stage A: 128x32 fp32 -> bf16 LDS
#pragma unroll
    for (int it = 0; it < 4; ++it) {
      int r = (tid >> 3) + it * 32;
      int c = (tid & 7) * 4;
      int grow = bm + r, gcol = k0 + c;
      f32x4 v = {0.f, 0.f, 0.f, 0.f};
      if (grow < M && gcol < kend) v = *(const f32x4*)(A + (size_t)grow * K + gcol);
      u16x4 h;
      h[0] = f2bf(v[0]); h[1] = f2bf(v[1]); h[2] = f2bf(v[2]); h[3] = f2bf(v[3]);
      *(u16x4*)&As[r * 40 + c] = h;
    }
    // stage B: 128x32 bf16
#pragma unroll
    for (int it = 0; it < 2; ++it) {
      int r = (tid >> 2) + it * 64;
      int c = (tid & 3) * 8;
      int grow = bn + r, gk = k0 + c;
      u16x8 bv = {0, 0, 0, 0, 0, 0, 0, 0};
      if (grow < N && gk < kend) bv = *(const u16x8*)(Bt + (size_t)grow * K + gk);
      *(u16x8*)&Bs[r * 40 + c] = bv;
    }
    __syncthreads();
    u16x8 ar[4], br[4];
#pragma unroll
    for (int i = 0; i < 4; ++i) ar[i] = *(const u16x8*)&As[(wm + i * 16 + l16) * 40 + koff];
#pragma unroll
    for (int j = 0; j < 4; ++j) br[j] = *(const u16x8*)&Bs[(wn + j * 16 + l16) * 40 + koff];
#pragma unroll
    for (int i = 0; i < 4; ++i)
#pragma unroll
      for (int j = 0; j < 4; ++j)
        acc[i][j] = __builtin_amdgcn_mfma_f32_16x16x32_bf16(
            __builtin_bit_cast(bf16x8, ar[i]), __builtin_bit_cast(bf16x8, br[j]),
            acc[i][j], 0, 0, 0);
    __syncthreads();
  }
  // epilogue: D[row=quad*4+r][col=l16] (m89/m91-verified mapping)
#pragma unroll
  for (int i = 0; i < 4; ++i)
#pragma unroll
    for (int rr = 0; rr < 4; ++rr) {
      int grow = bm + wm + i * 16 + quad * 4 + rr;
      if (grow >= M) continue;
#pragma unroll
      for (int j = 0; j < 4; ++j) {
        int gcol = bn + wn + j * 16 + l16;
        if (gcol >= N) continue;
        float v = acc[i][j][rr];
        if (atomic_out) atomicAdd(&C[(size_t)grow * N + gcol], v);
        else C[(size_t)grow * N + gcol] = v;
      }
    }
}

// ------------------------------------------------------------ GCN aggregate
// out[i] = relu(dinv[i]*(h[i]*dinv[i] + sum_in-edges h[s]*dinv[s]) + bias)
__global__ __launch_bounds__(256) void gcn_agg_k(
    const float* __restrict__ h, const int* __restrict__ rowptr,
    const int* __restrict__ col, const float* __restrict__ dinv,
    const float* __restrict__ bias, float* __restrict__ out, int n) {
  int wave = threadIdx.x >> 6, lane = threadIdx.x & 63;
  int node = blockIdx.x * 4 + wave;
  if (node >= n) return;
  int f = lane * 4;
  float di = dinv[node];
  f32x4 acc = *(const f32x4*)(h + (size_t)node * HD + f) * di;  // self loop
  int beg = rowptr[node], end = rowptr[node + 1];
  for (int e = beg; e < end; ++e) {
    int s = col[e];
    float w = dinv[s];
    f32x4 hv = *(const f32x4*)(h + (size_t)s * HD + f);
    acc += hv * w;
  }
  f32x4 b = *(const f32x4*)(bias + f);
  acc = acc * di + b;
#pragma unroll
  for (int q = 0; q < 4; ++q) acc[q] = fmaxf(acc[q], 0.f);
  *(f32x4*)(out + (size_t)node * HD + f) = acc;
}

// -------------------------------------------------------------- pooling
// mode 0: mean, 1: max.  src [n][F], dst row-stride dstride, col offset doff
__global__ void seg_pool_k(const float* __restrict__ src, int F,
                           const int* __restrict__ segs, const int* __restrict__ sege,
                           float* __restrict__ dst, int dstride, int doff, int mode) {
  int g = blockIdx.x;
  int f = blockIdx.y * 256 + threadIdx.x;
  if (f >= F) return;
  int s = segs[g], e = sege[g];
  float acc = (mode == 1) ? -INFINITY : 0.f;
  for (int i = s; i < e; ++i) {
    float v = src[(size_t)i * F + f];
    acc = (mode == 1) ? fmaxf(acc, v) : (acc + v);
  }
  if (mode == 0) acc /= (float)((e - s) > 0 ? (e - s) : 1);
  dst[(size_t)g * dstride + doff + f] = acc;
}

__global__ void root_gather_k(const float* __restrict__ data_x,
                              const int* __restrict__ rootindex, float* __restrict__ cat) {
  int g = blockIdx.x;
  int f = blockIdx.y * 256 + threadIdx.x;
  if (f >= RAWF) return;
  cat[(size_t)g * (2 * RAWF) + RAWF + f] = data_x[(size_t)rootindex[g] * RAWF + f];
}

// ----------------------------------------------------------- small epilogues
__global__ void bias_prelu_k(const float* __restrict__ in, const float* __restrict__ bias,
                             const float* __restrict__ pa, float* __restrict__ out,
                             int total, int cols) {
  int i = blockIdx.x * 256 + threadIdx.x;
  if (i >= total) return;
  float v = in[i] + bias[i % cols];
  float a = *pa;
  out[i] = (v >= 0.f) ? v : a * v;
}

// new_x = prelu(t1[128x512] @ Wl2[512x256] + bl2) -> pools[:,768:1024)
__global__ __launch_bounds__(256) void gemm_e_k(const float* __restrict__ t1,
                                                const float* __restrict__ Wl2,
                                                const float* __restrict__ bl2,
                                                const float* __restrict__ pa,
                                                float* __restrict__ pools) {
  int b = blockIdx.x, n = threadIdx.x;
  float acc = 0.f;
  for (int k = 0; k < 512; ++k) acc = fmaf(t1[b * 512 + k], Wl2[k * 256 + n], acc);
  acc += bl2[n];
  float a = *pa;
  acc = (acc >= 0.f) ? acc : a * acc;
  pools[(size_t)b * 1280 + 768 + n] = acc;
}

// logits = pools[128x1280] @ W5[1280x4] + b5 ; log_softmax
__global__ __launch_bounds__(256) void final_k(const float* __restrict__ pools,
                                               const float* __restrict__ W5,
                                               const float* __restrict__ b5,
                                               float* __restrict__ out) {
  __shared__ float red[256][4];
  int b = blockIdx.x, t = threadIdx.x;
  float a0 = 0, a1 = 0, a2 = 0, a3 = 0;
  for (int i = t; i < 1280; i += 256) {
    float p = pools[(size_t)b * 1280 + i];
    a0 = fmaf(p, W5[i * 4 + 0], a0);
    a1 = fmaf(p, W5[i * 4 + 1], a1);
    a2 = fmaf(p, W5[i * 4 + 2], a2);
    a3 = fmaf(p, W5[i * 4 + 3], a3);
  }
  red[t][0] = a0; red[t][1] = a1; red[t][2] = a2; red[t][3] = a3;
  __syncthreads();
  for (int off = 128; off >= 1; off >>= 1) {
    if (t < off)
      for (int c = 0; c < 4; ++c) red[t][c] += red[t + off][c];
    __syncthreads();
  }
  if (t == 0) {
    float z[4];
    for (int c = 0; c < 4; ++c) z[c] = red[0][c] + b5[c];
    float m = fmaxf(fmaxf(z[0], z[1]), fmaxf(z[2], z[3]));
    float s = 0.f;
    for (int c = 0; c < 4; ++c) s += expf(z[c] - m);
    float lse = logf(s);
    for (int c = 0; c < 4; ++c) out[b * 4 + c] = z[c] - m - lse;
  }
}

// ================================================================ launcher
extern "C" void kernel_launch(void* const* d_in, const int* in_sizes, int n_in,
                              void* d_out, int out_size, void* d_ws, size_t ws_size,
                              hipStream_t stream) {
  const float* graph_x = (const float*)d_in[0];
  const float* data_x  = (const float*)d_in[2];
  const int*   ei      = (const int*)d_in[3];   // [2][E]: src, dst
  const int*   rei     = (const int*)d_in[4];
  const int*   batch   = (const int*)d_in[5];
  const int*   rooti   = (const int*)d_in[7];
  const float* W1  = (const float*)d_in[8];   const float* b1  = (const float*)d_in[9];
  const float* Wc0 = (const float*)d_in[10];  const float* bc0 = (const float*)d_in[11];
  const float* Wc1 = (const float*)d_in[12];  const float* bc1 = (const float*)d_in[13];
  const float* Wc2 = (const float*)d_in[14];  const float* bc2 = (const float*)d_in[15];
  const float* Wl1 = (const float*)d_in[16];  const float* bl1 = (const float*)d_in[17];
  const float* Wl2 = (const float*)d_in[18];  const float* bl2 = (const float*)d_in[19];
  const float* pa  = (const float*)d_in[20];
  const float* W5  = (const float*)d_in[21];  const float* b5  = (const float*)d_in[22];
  float* out = (float*)d_out;

  char* ws = (char*)d_ws;
  size_t off = 0;
  auto take = [&](size_t bytes) -> void* {
    void* p = ws + off;
    off += (bytes + 255) & ~(size_t)255;
    return p;
  };
  int* deg1    = (int*)take(NN * 4);
  int* rowptr1 = (int*)take((NN + 1) * 4);
  int* cursor1 = (int*)take(NN * 4);
  int* col1    = (int*)take(EE * 4);
  float* dinv1 = (float*)take(NN * 4);
  int* deg2    = (int*)take(NN * 4);
  int* rowptr2 = (int*)take((NN + 1) * 4);
  int* cursor2 = (int*)take(NN * 4);
  int* col2    = (int*)take(EE * 4);
  float* dinv2 = (float*)take(NN * 4);
  int* segs = (int*)take(BG * 4);
  int* sege = (int*)take(BG * 4);
  unsigned short* W1t  = (unsigned short*)take((size_t)HD * FIN * 2);
  unsigned short* Wc0t = (unsigned short*)take((size_t)HD * RAWF * 2);
  unsigned short* Wc1t = (unsigned short*)take((size_t)HD * HD * 2);
  unsigned short* Wc2t = (unsigned short*)take((size_t)HD * HD * 2);
  unsigned short* Wl1t = (unsigned short*)take((size_t)512 * 10000 * 2);
  float* hA   = (float*)take((size_t)NN * HD * 4);
  float* hB   = (float*)take((size_t)NN * HD * 4);
  float* cat  = (float*)take((size_t)BG * 2 * RAWF * 4);
  float* Cd   = (float*)take((size_t)BG * 512 * 4);
  float* t1   = (float*)take((size_t)BG * 512 * 4);
  float* pools = (float*)take((size_t)BG * 1280 * 4);

  // ---- zero-init (ws is poisoned 0xAA every call)
  hipMemsetAsync(deg1, 0, NN * 4, stream);
  hipMemsetAsync(deg2, 0, NN * 4, stream);
  hipMemsetAsync(Cd, 0, (size_t)BG * 512 * 4, stream);

  // ---- CSR build for both graphs
  count_deg_k<<<ceil_div(EE, 256), 256, 0, stream>>>(ei + EE, deg1, EE);
  count_deg_k<<<ceil_div(EE, 256), 256, 0, stream>>>(rei + EE, deg2, EE);
  dinv_k<<<ceil_div(NN, 256), 256, 0, stream>>>(deg1, dinv1, NN);
  dinv_k<<<ceil_div(NN, 256), 256, 0, stream>>>(deg2, dinv2, NN);
  scan_k<<<1, 1024, 0, stream>>>(deg1, rowptr1, cursor1, NN);
  scan_k<<<1, 1024, 0, stream>>>(deg2, rowptr2, cursor2, NN);
  scatter_k<<<ceil_div(EE, 256), 256, 0, stream>>>(ei, ei + EE, cursor1, col1, EE);
  scatter_k<<<ceil_div(EE, 256), 256, 0, stream>>>(rei, rei + EE, cursor2, col2, EE);
  segbounds_k<<<ceil_div(NN, 256), 256, 0, stream>>>(batch, segs, sege, NN);

  // ---- weight transposes (fp32 [K][N] -> bf16 [N][K])
  transpose_cvt_k<<<dim3(ceil_div(FIN, 256), HD), 256, 0, stream>>>(W1, W1t, FIN, HD);
  transpose_cvt_k<<<dim3(ceil_div(RAWF, 256), HD), 256, 0, stream>>>(Wc0, Wc0t, RAWF, HD);
  transpose_cvt_k<<<dim3(ceil_div(HD, 256), HD), 256, 0, stream>>>(Wc1, Wc1t, HD, HD);
  transpose_cvt_k<<<dim3(ceil_div(HD, 256), HD), 256, 0, stream>>>(Wc2, Wc2t, HD, HD);
  transpose_cvt_k<<<dim3(ceil_div(10000, 256), 512), 256, 0, stream>>>(Wl1, Wl1t, 10000, 512);

  int mt = ceil_div(NN, 128);  // 157 M-tiles

  // ---- branch 1: GCN(graph_x) -> relu -> segment_max
  gemm_bf16_k<<<dim3(HD / 128, mt, 1), 256, 0, stream>>>(graph_x, W1t, hA, NN, HD, FIN, FIN, 0);
  gcn_agg_k<<<ceil_div(NN, 4), 256, 0, stream>>>(hA, rowptr1, col1, dinv1, b1, hB, NN);
  seg_pool_k<<<dim3(BG, 1), 256, 0, stream>>>(hB, HD, segs, sege, pools, 1280, 1024, 1);

  // ---- branch 3: three GCN layers over raw graph, mean pool each
  gemm_bf16_k<<<dim3(HD / 128, mt, 1), 256, 0, stream>>>(data_x, Wc0t, hA, NN, HD, RAWF, RAWF, 0);
  gcn_agg_k<<<ceil_div(NN, 4), 256, 0, stream>>>(hA, rowptr2, col2, dinv2, bc0, hB, NN);
  seg_pool_k<<<dim3(BG, 1), 256, 0, stream>>>(hB, HD, segs, sege, pools, 1280, 0, 0);

  gemm_bf16_k<<<dim3(HD / 128, mt, 1), 256, 0, stream>>>(hB, Wc1t, hA, NN, HD, HD, HD, 0);
  gcn_agg_k<<<ceil_div(NN, 4), 256, 0, stream>>>(hA, rowptr2, col2, dinv2, bc1, hB, NN);
  seg_pool_k<<<dim3(BG, 1), 256, 0, stream>>>(hB, HD, segs, sege, pools, 1280, 256, 0);

  gemm_bf16_k<<<dim3(HD / 128, mt, 1), 256, 0, stream>>>(hB, Wc2t, hA, NN, HD, HD, HD, 0);
  gcn_agg_k<<<ceil_div(NN, 4), 256, 0, stream>>>(hA, rowptr2, col2, dinv2, bc2, hB, NN);
  seg_pool_k<<<dim3(BG, 1), 256, 0, stream>>>(hB, HD, segs, sege, pools, 1280, 512, 0);

  // ---- branch 2: [mean(data_x) | root rows] @ Wl1 -> prelu -> @ Wl2 -> prelu
  seg_pool_k<<<dim3(BG, ceil_div(RAWF, 256)), 256, 0, stream>>>(data_x, RAWF, segs, sege,
                                                                cat, 2 * RAWF, 0, 0);
  root_gather_k<<<dim3(BG, ceil_div(RAWF, 256)), 256, 0, stream>>>(data_x, rooti, cat);
  // split-K (32 chunks of 320) with atomic accumulate into zeroed Cd
  gemm_bf16_k<<<dim3(512 / 128, 1, 32), 256, 0, stream>>>(cat, Wl1t, Cd, BG, 512, 10000, 320, 1);
  bias_prelu_k<<<ceil_div(BG * 512, 256), 256, 0, stream>>>(Cd, bl1, pa, t1, BG * 512, 512);
  gemm_e_k<<<BG, 256, 0, stream>>>(t1, Wl2, bl2, pa, pools);

  // ---- final concat @ W5 + log_softmax
  final_k<<<BG, 256, 0, stream>>>(pools, W5, b5, out);
}

// Round 2
// 1510.129 us; speedup vs baseline: 1.2468x; 1.2468x over previous
//
#include <hip/hip_runtime.h>
#include <math.h>

// Problem dims (fixed by reference setup_inputs)
#define NN   20000   // nodes
#define BG   128     // graphs
#define EE   320000  // edges
#define FIN  768
#define RAWF 5000
#define HD   256
#define NC   4

typedef __attribute__((ext_vector_type(4))) float          f32x4;
typedef __attribute__((ext_vector_type(8))) unsigned short u16x8;
typedef __attribute__((ext_vector_type(4))) unsigned short u16x4;
typedef __attribute__((ext_vector_type(8))) __bf16         bf16x8;

__device__ __forceinline__ unsigned short f2bf(float f) {
  unsigned u = __float_as_uint(f);
  u += 0x7FFFu + ((u >> 16) & 1u);
  return (unsigned short)(u >> 16);
}

static inline int ceil_div(int a, int b) { return (a + b - 1) / b; }

// ---------------------------------------------------------------- CSR build
__global__ void count_deg_k(const int* __restrict__ dst, int* __restrict__ deg, int e) {
  int i = blockIdx.x * 256 + threadIdx.x;
  if (i < e) atomicAdd(&deg[dst[i]], 1);
}

// hierarchical scan, stage 1: per-block (1024) inclusive scan via shuffles
__global__ __launch_bounds__(1024) void scan_local_k(const int* __restrict__ deg,
                                                     int* __restrict__ excl,
                                                     int* __restrict__ bsum, int n) {
  __shared__ int wsum[16];
  int t = threadIdx.x, lane = t & 63, w = t >> 6;
  int i = blockIdx.x * 1024 + t;
  int v = (i < n) ? deg[i] : 0;
  int acc = v;
#pragma unroll
  for (int off = 1; off < 64; off <<= 1) {
    int o = __shfl_up(acc, off, 64);
    if (lane >= off) acc += o;
  }
  if (lane == 63) wsum[w] = acc;
  __syncthreads();
  if (w == 0 && lane < 16) {
    int s = wsum[lane];
#pragma unroll
    for (int off = 1; off < 16; off <<= 1) {
      int o = __shfl_up(s, off, 64);
      if (lane >= off) s += o;
    }
    wsum[lane] = s;
  }
  __syncthreads();
  if (w > 0) acc += wsum[w - 1];
  if (i < n) excl[i] = acc - v;
  if (t == 1023) bsum[blockIdx.x] = acc;
}

// stage 2: serial scan of block sums (nb ~ 20), writes rowptr[n]
__global__ void scan_tops_k(const int* __restrict__ bsum, int* __restrict__ boff,
                            int* __restrict__ rowptr_end, int nb) {
  if (threadIdx.x == 0) {
    int run = 0;
    for (int b = 0; b < nb; ++b) { boff[b] = run; run += bsum[b]; }
    *rowptr_end = run;
  }
}

// stage 3: add block offsets -> rowptr & cursor; fuse dinv = rsqrt(deg+1)
__global__ __launch_bounds__(1024) void scan_add_k(const int* __restrict__ excl,
                                                   const int* __restrict__ boff,
                                                   const int* __restrict__ deg,
                                                   int* __restrict__ rowptr,
                                                   int* __restrict__ cursor,
                                                   float* __restrict__ dinv, int n) {
  int i = blockIdx.x * 1024 + threadIdx.x;
  if (i < n) {
    int v = excl[i] + boff[blockIdx.x];
    rowptr[i] = v;
    cursor[i] = v;
    dinv[i] = rsqrtf((float)(deg[i] + 1));
  }
}

__global__ void scatter_k(const int* __restrict__ src, const int* __restrict__ dst,
                          int* __restrict__ cursor, int* __restrict__ col, int e) {
  int i = blockIdx.x * 256 + threadIdx.x;
  if (i < e) {
    int d = dst[i];
    int p = atomicAdd(&cursor[d], 1);
    col[p] = src[i];
  }
}

__global__ void segbounds_k(const int* __restrict__ batch, int* __restrict__ s,
                            int* __restrict__ e, int n) {
  int i = blockIdx.x * 256 + threadIdx.x;
  if (i >= n) return;
  int b = batch[i];
  if (i == 0 || batch[i - 1] != b) s[b] = i;
  if (i == n - 1 || batch[i + 1] != b) e[b] = i + 1;
}

// ------------------------------------------------- weight transpose+convert
// in [K][N] fp32 -> out [N][K] bf16, LDS-tiled 32x32 (coalesced both sides)
__global__ __launch_bounds__(256) void transpose_cvt_k(const float* __restrict__ in,
                                                       unsigned short* __restrict__ out,
                                                       int K, int N) {
  __shared__ unsigned short tile[32][34];
  int tx = threadIdx.x & 31, ty = threadIdx.x >> 5;  // 32 x 8
  int k0 = blockIdx.x * 32, n0 = blockIdx.y * 32;
#pragma unroll
  for (int r = 0; r < 32; r += 8) {
    int k = k0 + ty + r, n = n0 + tx;
    float v = (k < K && n < N) ? in[(size_t)k * N + n] : 0.f;
    tile[ty + r][tx] = f2bf(v);
  }
  __syncthreads();
#pragma unroll
  for (int r = 0; r < 32; r += 8) {
    int n = n0 + ty + r, k = k0 + tx;
    if (n < N && k < K) out[(size_t)n * K + k] = tile[tx][ty + r];
  }
}

// ------------------------------------------------------------- MFMA GEMM
// C[M][N] (+)= A[M][K] fp32 @ Bt[N][K] bf16, tiles 128x128x32, 256 thr = 4 waves
__global__ __launch_bounds__(256) void gemm_bf16_k(
    const float* __restrict__ A, const unsigned short* __restrict__ Bt,
    float* __restrict__ C, int M, int N, int K, int kchunk, int atomic_out) {
  __shared__ unsigned short As[128 * 40];  // pad 32->40: 2-way bank alias only
  __shared__ unsigned short Bs[128 * 40];
  int tid = threadIdx.x;
  int lane = tid & 63, wave = tid >> 6;
  int quad = lane >> 4, l16 = lane & 15;
  int koff = quad * 8;
  int bn = blockIdx.x * 128;   // N-tile fastest -> paired M-tiles share A in cache
  int bm = blockIdx.y * 128;
  int wm = (wave >> 1) * 64, wn = (wave & 1) * 64;
  int kbegin = blockIdx.z * kchunk;
  int kend = kbegin + kchunk; if (kend > K) kend = K;

  f32x4 acc[4][4] = {};

  for (int k0 = kbegin; k0 < kend; k0 += 32) {
    // stage A: 128x32 fp32 -> bf16 LDS
#pragma unroll
    for (int it = 0; it < 4; ++it) {
      int r = (tid >> 3) + it * 32;
      int c = (tid & 7) * 4;
      int grow = bm + r, gcol = k0 + c;
      f32x4 v = {0.f, 0.f, 0.f, 0.f};
      if (grow < M && gcol < kend) v = *(const f32x4*)(A + (size_t)grow * K + gcol);
      u16x4 h;
      h[0] = f2bf(v[0]); h[1] = f2bf(v[1]); h[2] = f2bf(v[2]); h[3] = f2bf(v[3]);
      *(u16x4*)&As[r * 40 + c] = h;
    }
    // stage B: 128x32 bf16
#pragma unroll
    for (int it = 0; it < 2; ++it) {
      int r = (tid >> 2) + it * 64;
      int c = (tid & 3) * 8;
      int grow = bn + r, gk = k0 + c;
      u16x8 bv = {0, 0, 0, 0, 0, 0, 0, 0};
      if (grow < N && gk < kend) bv = *(const u16x8*)(Bt + (size_t)grow * K + gk);
      *(u16x8*)&Bs[r * 40 + c] = bv;
    }
    __syncthreads();
    u16x8 ar[4], br[4];
#pragma unroll
    for (int i = 0; i < 4; ++i) ar[i] = *(const u16x8*)&As[(wm + i * 16 + l16) * 40 + koff];
#pragma unroll
    for (int j = 0; j < 4; ++j) br[j] = *(const u16x8*)&Bs[(wn + j * 16 + l16) * 40 + koff];
#pragma unroll
    for (int i = 0; i < 4; ++i)
#pragma unroll
      for (int j = 0; j < 4; ++j)
        acc[i][j] = __builtin_amdgcn_mfma_f32_16x16x32_bf16(
            __builtin_bit_cast(bf16x8, ar[i]), __builtin_bit_cast(bf16x8, br[j]),
            acc[i][j], 0, 0, 0);
    __syncthreads();
  }
  // epilogue: D[row=quad*4+r][col=l16] (m89/m91-verified mapping)
#pragma unroll
  for (int i = 0; i < 4; ++i)
#pragma unroll
    for (int rr = 0; rr < 4; ++rr) {
      int grow = bm + wm + i * 16 + quad * 4 + rr;
      if (grow >= M) continue;
#pragma unroll
      for (int j = 0; j < 4; ++j) {
        int gcol = bn + wn + j * 16 + l16;
        if (gcol >= N) continue;
        float v = acc[i][j][rr];
        if (atomic_out) atomicAdd(&C[(size_t)grow * N + gcol], v);
        else C[(size_t)grow * N + gcol] = v;
      }
    }
}

// ------------------------------------------------------------ GCN aggregate
// out[i] = relu(dinv[i]*(h[i]*dinv[i] + sum_in-edges h[s]*dinv[s]) + bias)
__global__ __launch_bounds__(256) void gcn_agg_k(
    const float* __restrict__ h, const int* __restrict__ rowptr,
    const int* __restrict__ col, const float* __restrict__ dinv,
    const float* __restrict__ bias, float* __restrict__ out, int n) {
  int wave = threadIdx.x >> 6, lane = threadIdx.x & 63;
  int node = blockIdx.x * 4 + wave;
  if (node >= n) return;
  int f = lane * 4;
  float di = dinv[node];
  f32x4 acc = *(const f32x4*)(h + (size_t)node * HD + f) * di;  // self loop
  int beg = rowptr[node], end = rowptr[node + 1];
  int e = beg;
  // unroll x4: keep 4 independent gather rows in flight
  for (; e + 4 <= end; e += 4) {
    int s0 = col[e], s1 = col[e + 1], s2 = col[e + 2], s3 = col[e + 3];
    float w0 = dinv[s0], w1 = dinv[s1], w2 = dinv[s2], w3 = dinv[s3];
    f32x4 h0 = *(const f32x4*)(h + (size_t)s0 * HD + f);
    f32x4 h1 = *(const f32x4*)(h + (size_t)s1 * HD + f);
    f32x4 h2 = *(const f32x4*)(h + (size_t)s2 * HD + f);
    f32x4 h3 = *(const f32x4*)(h + (size_t)s3 * HD + f);
    acc += h0 * w0;
    acc += h1 * w1;
    acc += h2 * w2;
    acc += h3 * w3;
  }
  for (; e < end; ++e) {
    int s = col[e];
    float w = dinv[s];
    f32x4 hv = *(const f32x4*)(h + (size_t)s * HD + f);
    acc += hv * w;
  }
  f32x4 b = *(const f32x4*)(bias + f);
  acc = acc * di + b;
#pragma unroll
  for (int q = 0; q < 4; ++q) acc[q] = fmaxf(acc[q], 0.f);
  *(f32x4*)(out + (size_t)node * HD + f) = acc;
}

// -------------------------------------------------------------- pooling
// mode 0: mean, 1: max.  src [n][F], dst row-stride dstride, col offset doff
__global__ void seg_pool_k(const float* __restrict__ src, int F,
                           const int* __restrict__ segs, const int* __restrict__ sege,
                           float* __restrict__ dst, int dstride, int doff, int mode) {
  int g = blockIdx.x;
  int f = blockIdx.y * 256 + threadIdx.x;
  if (f >= F) return;
  int s = segs[g], e = sege[g];
  float a0, a1, a2, a3;
  if (mode == 1) { a0 = a1 = a2 = a3 = -INFINITY; } else { a0 = a1 = a2 = a3 = 0.f; }
  int i = s;
  for (; i + 4 <= e; i += 4) {
    float v0 = src[(size_t)(i + 0) * F + f];
    float v1 = src[(size_t)(i + 1) * F + f];
    float v2 = src[(size_t)(i + 2) * F + f];
    float v3 = src[(size_t)(i + 3) * F + f];
    if (mode == 1) { a0 = fmaxf(a0, v0); a1 = fmaxf(a1, v1); a2 = fmaxf(a2, v2); a3 = fmaxf(a3, v3); }
    else           { a0 += v0; a1 += v1; a2 += v2; a3 += v3; }
  }
  for (; i < e; ++i) {
    float v = src[(size_t)i * F + f];
    if (mode == 1) a0 = fmaxf(a0, v); else a0 += v;
  }
  float acc;
  if (mode == 1) acc = fmaxf(fmaxf(a0, a1), fmaxf(a2, a3));
  else {
    acc = (a0 + a1) + (a2 + a3);
    acc /= (float)((e - s) > 0 ? (e - s) : 1);
  }
  dst[(size_t)g * dstride + doff + f] = acc;
}

__global__ void root_gather_k(const float* __restrict__ data_x,
                              const int* __restrict__ rootindex, float* __restrict__ cat) {
  int g = blockIdx.x;
  int f = blockIdx.y * 256 + threadIdx.x;
  if (f >= RAWF) return;
  cat[(size_t)g * (2 * RAWF) + RAWF + f] = data_x[(size_t)rootindex[g] * RAWF + f];
}

// ----------------------------------------------------------- small epilogues
__global__ void bias_prelu_k(const float* __restrict__ in, const float* __restrict__ bias,
                             const float* __restrict__ pa, float* __restrict__ out,
                             int total, int cols) {
  int i = blockIdx.x * 256 + threadIdx.x;
  if (i >= total) return;
  float v = in[i] + bias[i % cols];
  float a = *pa;
  out[i] = (v >= 0.f) ? v : a * v;
}

// new_x = prelu(t1[128x512] @ Wl2[512x256] + bl2) -> pools[:,768:1024)
__global__ __launch_bounds__(256) void gemm_e_k(const float* __restrict__ t1,
                                                const float* __restrict__ Wl2,
                                                const float* __restrict__ bl2,
                                                const float* __restrict__ pa,
                                                float* __restrict__ pools) {
  int b = blockIdx.x, n = threadIdx.x;
  float acc = 0.f;
  for (int k = 0; k < 512; ++k) acc = fmaf(t1[b * 512 + k], Wl2[k * 256 + n], acc);
  acc += bl2[n];
  float a = *pa;
  acc = (acc >= 0.f) ? acc : a * acc;
  pools[(size_t)b * 1280 + 768 + n] = acc;
}

// logits = pools[128x1280] @ W5[1280x4] + b5 ; log_softmax
__global__ __launch_bounds__(256) void final_k(const float* __restrict__ pools,
                                               const float* __restrict__ W5,
                                               const float* __restrict__ b5,
                                               float* __restrict__ out) {
  __shared__ float red[256][4];
  int b = blockIdx.x, t = threadIdx.x;
  float a0 = 0, a1 = 0, a2 = 0, a3 = 0;
  for (int i = t; i < 1280; i += 256) {
    float p = pools[(size_t)b * 1280 + i];
    a0 = fmaf(p, W5[i * 4 + 0], a0);
    a1 = fmaf(p, W5[i * 4 + 1], a1);
    a2 = fmaf(p, W5[i * 4 + 2], a2);
    a3 = fmaf(p, W5[i * 4 + 3], a3);
  }
  red[t][0] = a0; red[t][1] = a1; red[t][2] = a2; red[t][3] = a3;
  __syncthreads();
  for (int off = 128; off >= 1; off >>= 1) {
    if (t < off)
      for (int c = 0; c < 4; ++c) red[t][c] += red[t + off][c];
    __syncthreads();
  }
  if (t == 0) {
    float z[4];
    for (int c = 0; c < 4; ++c) z[c] = red[0][c] + b5[c];
    float m = fmaxf(fmaxf(z[0], z[1]), fmaxf(z[2], z[3]));
    float s = 0.f;
    for (int c = 0; c < 4; ++c) s += expf(z[c] - m);
    float lse = logf(s);
    for (int c = 0; c < 4; ++c) out[b * 4 + c] = z[c] - m - lse;
  }
}

// ================================================================ launcher
extern "C" void kernel_launch(void* const* d_in, const int* in_sizes, int n_in,
                              void* d_out, int out_size, void* d_ws, size_t ws_size,
                              hipStream_t stream) {
  const float* graph_x = (const float*)d_in[0];
  const float* data_x  = (const float*)d_in[2];
  const int*   ei      = (const int*)d_in[3];   // [2][E]: src, dst
  const int*   rei     = (const int*)d_in[4];
  const int*   batch   = (const int*)d_in[5];
  const int*   rooti   = (const int*)d_in[7];
  const float* W1  = (const float*)d_in[8];   const float* b1  = (const float*)d_in[9];
  const float* Wc0 = (const float*)d_in[10];  const float* bc0 = (const float*)d_in[11];
  const float* Wc1 = (const float*)d_in[12];  const float* bc1 = (const float*)d_in[13];
  const float* Wc2 = (const float*)d_in[14];  const float* bc2 = (const float*)d_in[15];
  const float* Wl1 = (const float*)d_in[16];  const float* bl1 = (const float*)d_in[17];
  const float* Wl2 = (const float*)d_in[18];  const float* bl2 = (const float*)d_in[19];
  const float* pa  = (const float*)d_in[20];
  const float* W5  = (const float*)d_in[21];  const float* b5  = (const float*)d_in[22];
  float* out = (float*)d_out;

  char* ws = (char*)d_ws;
  size_t off = 0;
  auto take = [&](size_t bytes) -> void* {
    void* p = ws + off;
    off += (bytes + 255) & ~(size_t)255;
    return p;
  };
  const int NB = ceil_div(NN, 1024);  // scan blocks (20)
  int* deg1    = (int*)take(NN * 4);
  int* rowptr1 = (int*)take((NN + 1) * 4);
  int* cursor1 = (int*)take(NN * 4);
  int* col1    = (int*)take(EE * 4);
  float* dinv1 = (float*)take(NN * 4);
  int* deg2    = (int*)take(NN * 4);
  int* rowptr2 = (int*)take((NN + 1) * 4);
  int* cursor2 = (int*)take(NN * 4);
  int* col2    = (int*)take(EE * 4);
  float* dinv2 = (float*)take(NN * 4);
  int* excl    = (int*)take(NN * 4);
  int* bsum    = (int*)take(NB * 4);
  int* boff    = (int*)take(NB * 4);
  int* segs = (int*)take(BG * 4);
  int* sege = (int*)take(BG * 4);
  unsigned short* W1t  = (unsigned short*)take((size_t)HD * FIN * 2);
  unsigned short* Wc0t = (unsigned short*)take((size_t)HD * RAWF * 2);
  unsigned short* Wc1t = (unsigned short*)take((size_t)HD * HD * 2);
  unsigned short* Wc2t = (unsigned short*)take((size_t)HD * HD * 2);
  unsigned short* Wl1t = (unsigned short*)take((size_t)512 * 10000 * 2);
  float* hA   = (float*)take((size_t)NN * HD * 4);
  float* hB   = (float*)take((size_t)NN * HD * 4);
  float* cat  = (float*)take((size_t)BG * 2 * RAWF * 4);
  float* Cd   = (float*)take((size_t)BG * 512 * 4);
  float* t1   = (float*)take((size_t)BG * 512 * 4);
  float* pools = (float*)take((size_t)BG * 1280 * 4);

  // ---- zero-init (ws is poisoned 0xAA every call)
  hipMemsetAsync(deg1, 0, NN * 4, stream);
  hipMemsetAsync(deg2, 0, NN * 4, stream);
  hipMemsetAsync(Cd, 0, (size_t)BG * 512 * 4, stream);

  // ---- CSR build for both graphs (hierarchical scan)
  count_deg_k<<<ceil_div(EE, 256), 256, 0, stream>>>(ei + EE, deg1, EE);
  count_deg_k<<<ceil_div(EE, 256), 256, 0, stream>>>(rei + EE, deg2, EE);

  scan_local_k<<<NB, 1024, 0, stream>>>(deg1, excl, bsum, NN);
  scan_tops_k<<<1, 64, 0, stream>>>(bsum, boff, rowptr1 + NN, NB);
  scan_add_k<<<NB, 1024, 0, stream>>>(excl, boff, deg1, rowptr1, cursor1, dinv1, NN);
  scatter_k<<<ceil_div(EE, 256), 256, 0, stream>>>(ei, ei + EE, cursor1, col1, EE);

  scan_local_k<<<NB, 1024, 0, stream>>>(deg2, excl, bsum, NN);
  scan_tops_k<<<1, 64, 0, stream>>>(bsum, boff, rowptr2 + NN, NB);
  scan_add_k<<<NB, 1024, 0, stream>>>(excl, boff, deg2, rowptr2, cursor2, dinv2, NN);
  scatter_k<<<ceil_div(EE, 256), 256, 0, stream>>>(rei, rei + EE, cursor2, col2, EE);

  segbounds_k<<<ceil_div(NN, 256), 256, 0, stream>>>(batch, segs, sege, NN);

  // ---- weight transposes (fp32 [K][N] -> bf16 [N][K]), tiled
  transpose_cvt_k<<<dim3(ceil_div(FIN, 32), ceil_div(HD, 32)), 256, 0, stream>>>(W1, W1t, FIN, HD);
  transpose_cvt_k<<<dim3(ceil_div(RAWF, 32), ceil_div(HD, 32)), 256, 0, stream>>>(Wc0, Wc0t, RAWF, HD);
  transpose_cvt_k<<<dim3(ceil_div(HD, 32), ceil_div(HD, 32)), 256, 0, stream>>>(Wc1, Wc1t, HD, HD);
  transpose_cvt_k<<<dim3(ceil_div(HD, 32), ceil_div(HD, 32)), 256, 0, stream>>>(Wc2, Wc2t, HD, HD);
  transpose_cvt_k<<<dim3(ceil_div(10000, 32), ceil_div(512, 32)), 256, 0, stream>>>(Wl1, Wl1t, 10000, 512);

  int mt = ceil_div(NN, 128);  // 157 M-tiles

  // ---- branch 1: GCN(graph_x) -> relu -> segment_max  (split-K z=3)
  hipMemsetAsync(hA, 0, (size_t)NN * HD * 4, stream);
  gemm_bf16_k<<<dim3(HD / 128, mt, 3), 256, 0, stream>>>(graph_x, W1t, hA, NN, HD, FIN, 256, 1);
  gcn_agg_k<<<ceil_div(NN, 4), 256, 0, stream>>>(hA, rowptr1, col1, dinv1, b1, hB, NN);
  seg_pool_k<<<dim3(BG, 1), 256, 0, stream>>>(hB, HD, segs, sege, pools, 1280, 1024, 1);

  // ---- branch 3: three GCN layers over raw graph, mean pool each
  hipMemsetAsync(hA, 0, (size_t)NN * HD * 4, stream);
  gemm_bf16_k<<<dim3(HD / 128, mt, 4), 256, 0, stream>>>(data_x, Wc0t, hA, NN, HD, RAWF, 1280, 1);
  gcn_agg_k<<<ceil_div(NN, 4), 256, 0, stream>>>(hA, rowptr2, col2, dinv2, bc0, hB, NN);
  seg_pool_k<<<dim3(BG, 1), 256, 0, stream>>>(hB, HD, segs, sege, pools, 1280, 0, 0);

  hipMemsetAsync(hA, 0, (size_t)NN * HD * 4, stream);
  gemm_bf16_k<<<dim3(HD / 128, mt, 2), 256, 0, stream>>>(hB, Wc1t, hA, NN, HD, HD, 128, 1);
  gcn_agg_k<<<ceil_div(NN, 4), 256, 0, stream>>>(hA, rowptr2, col2, dinv2, bc1, hB, NN);
  seg_pool_k<<<dim3(BG, 1), 256, 0, stream>>>(hB, HD, segs, sege, pools, 1280, 256, 0);

  hipMemsetAsync(hA, 0, (size_t)NN * HD * 4, stream);
  gemm_bf16_k<<<dim3(HD / 128, mt, 2), 256, 0, stream>>>(hB, Wc2t, hA, NN, HD, HD, 128, 1);
  gcn_agg_k<<<ceil_div(NN, 4), 256, 0, stream>>>(hA, rowptr2, col2, dinv2, bc2, hB, NN);
  seg_pool_k<<<dim3(BG, 1), 256, 0, stream>>>(hB, HD, segs, sege, pools, 1280, 512, 0);

  // ---- branch 2: [mean(data_x) | root rows] @ Wl1 -> prelu -> @ Wl2 -> prelu
  seg_pool_k<<<dim3(BG, ceil_div(RAWF, 256)), 256, 0, stream>>>(data_x, RAWF, segs, sege,
                                                                cat, 2 * RAWF, 0, 0);
  root_gather_k<<<dim3(BG, ceil_div(RAWF, 256)), 256, 0, stream>>>(data_x, rooti, cat);
  // split-K (32 chunks of 320) with atomic accumulate into zeroed Cd
  gemm_bf16_k<<<dim3(512 / 128, 1, 32), 256, 0, stream>>>(cat, Wl1t, Cd, BG, 512, 10000, 320, 1);
  bias_prelu_k<<<ceil_div(BG * 512, 256), 256, 0, stream>>>(Cd, bl1, pa, t1, BG * 512, 512);
  gemm_e_k<<<BG, 256, 0, stream>>>(t1, Wl2, bl2, pa, pools);

  // ---- final concat @ W5 + log_softmax
  final_k<<<BG, 256, 0, stream>>>(pools, W5, b5, out);
}

// Round 3
// 1354.438 us; speedup vs baseline: 1.3901x; 1.1149x over previous
//
#include <hip/hip_runtime.h>
#include <math.h>

// Problem dims (fixed by reference setup_inputs)
#define NN   20000   // nodes
#define BG   128     // graphs
#define EE   320000  // edges
#define FIN  768
#define RAWF 5000
#define KP   5120    // padded raw K (mult of 32)
#define CATK 10240   // padded 2*RAWF
#define HD   256
#define NC   4

typedef __attribute__((ext_vector_type(4))) float          f32x4;
typedef __attribute__((ext_vector_type(8))) unsigned short u16x8;
typedef __attribute__((ext_vector_type(4))) unsigned short u16x4;
typedef __attribute__((ext_vector_type(8))) __bf16         bf16x8;

__device__ __forceinline__ unsigned short f2bf(float f) {
  unsigned u = __float_as_uint(f);
  u += 0x7FFFu + ((u >> 16) & 1u);
  return (unsigned short)(u >> 16);
}
__device__ __forceinline__ float bf2f(unsigned short u) {
  return __uint_as_float((unsigned)u << 16);
}

static inline int ceil_div(int a, int b) { return (a + b - 1) / b; }

// ---------------------------------------------------------------- CSR build
// both graphs in one launch: i<EE -> graph1 dst, else graph2 dst
__global__ void count_deg2_k(const int* __restrict__ ei, const int* __restrict__ rei,
                             int* __restrict__ deg1, int* __restrict__ deg2) {
  int i = blockIdx.x * 256 + threadIdx.x;
  if (i < EE) atomicAdd(&deg1[ei[EE + i]], 1);
  else if (i < 2 * EE) atomicAdd(&deg2[rei[i]], 1);  // rei[EE + (i-EE)] == rei[i]
}

// hierarchical scan stage 1 (blockIdx.y selects graph)
__global__ __launch_bounds__(1024) void scan_local_k(const int* __restrict__ deg1,
                                                     const int* __restrict__ deg2,
                                                     int* __restrict__ excl,
                                                     int* __restrict__ bsum, int nb) {
  const int* deg = blockIdx.y ? deg2 : deg1;
  int* ex = excl + (size_t)blockIdx.y * NN;
  int* bs = bsum + (size_t)blockIdx.y * nb;
  __shared__ int wsum[16];
  int t = threadIdx.x, lane = t & 63, w = t >> 6;
  int i = blockIdx.x * 1024 + t;
  int v = (i < NN) ? deg[i] : 0;
  int acc = v;
#pragma unroll
  for (int off = 1; off < 64; off <<= 1) {
    int o = __shfl_up(acc, off, 64);
    if (lane >= off) acc += o;
  }
  if (lane == 63) wsum[w] = acc;
  __syncthreads();
  if (w == 0 && lane < 16) {
    int s = wsum[lane];
#pragma unroll
    for (int off = 1; off < 16; off <<= 1) {
      int o = __shfl_up(s, off, 64);
      if (lane >= off) s += o;
    }
    wsum[lane] = s;
  }
  __syncthreads();
  if (w > 0) acc += wsum[w - 1];
  if (i < NN) ex[i] = acc - v;
  if (t == 1023) bs[blockIdx.x] = acc;
}

__global__ void scan_tops_k(const int* __restrict__ bsum, int* __restrict__ boff,
                            int* __restrict__ end1, int* __restrict__ end2, int nb) {
  if (threadIdx.x == 0) {
    int run = 0;
    for (int b = 0; b < nb; ++b) { boff[b] = run; run += bsum[b]; }
    *end1 = run;
    run = 0;
    for (int b = 0; b < nb; ++b) { boff[nb + b] = run; run += bsum[nb + b]; }
    *end2 = run;
  }
}

__global__ __launch_bounds__(1024) void scan_add_k(
    const int* __restrict__ excl, const int* __restrict__ boff,
    const int* __restrict__ deg1, const int* __restrict__ deg2,
    int* __restrict__ rp1, int* __restrict__ rp2,
    int* __restrict__ cur1, int* __restrict__ cur2,
    float* __restrict__ dv1, float* __restrict__ dv2, int nb) {
  int y = blockIdx.y;
  const int* deg = y ? deg2 : deg1;
  int* rp = y ? rp2 : rp1;
  int* cur = y ? cur2 : cur1;
  float* dv = y ? dv2 : dv1;
  int i = blockIdx.x * 1024 + threadIdx.x;
  if (i < NN) {
    int v = excl[(size_t)y * NN + i] + boff[y * nb + blockIdx.x];
    rp[i] = v;
    cur[i] = v;
    dv[i] = rsqrtf((float)(deg[i] + 1));
  }
}

__global__ void scatter_k(const int* __restrict__ ei, const int* __restrict__ rei,
                          int* __restrict__ cur1, int* __restrict__ cur2,
                          int* __restrict__ col1, int* __restrict__ col2) {
  int i = blockIdx.x * 256 + threadIdx.x;
  int y = blockIdx.y;
  if (i < EE) {
    const int* e = y ? rei : ei;
    int* cur = y ? cur2 : cur1;
    int* col = y ? col2 : col1;
    int d = e[EE + i];
    int p = atomicAdd(&cur[d], 1);
    col[p] = e[i];
  }
}

__global__ void segbounds_k(const int* __restrict__ batch, int* __restrict__ s,
                            int* __restrict__ e, int n) {
  int i = blockIdx.x * 256 + threadIdx.x;
  if (i >= n) return;
  int b = batch[i];
  if (i == 0 || batch[i - 1] != b) s[b] = i;
  if (i == n - 1 || batch[i + 1] != b) e[b] = i + 1;
}

// ------------------------------------------------- batched weight transpose
// in [K][N] fp32 -> out [N][Kout] bf16, zero-fill K..Kout. 5 matrices, 1 launch.
__global__ __launch_bounds__(256) void trans_k(
    const float* __restrict__ i0, unsigned short* __restrict__ o0,   // W1  768x256 ->768
    const float* __restrict__ i1, unsigned short* __restrict__ o1,   // Wc0 5000x256 ->5120
    const float* __restrict__ i2, unsigned short* __restrict__ o2,   // Wc1 256x256
    const float* __restrict__ i3, unsigned short* __restrict__ o3,   // Wc2 256x256
    const float* __restrict__ i4, unsigned short* __restrict__ o4) { // Wl1 10000x512 ->10240
  __shared__ unsigned short tile[32][34];
  int b = blockIdx.x;
  const float* in; unsigned short* out;
  int K, N, Kout, tx, lid;
  if (b < 192)        { in=i0; out=o0; K=768;   N=256; Kout=768;   tx=24;  lid=b; }
  else if (b < 1472)  { in=i1; out=o1; K=5000;  N=256; Kout=5120;  tx=160; lid=b-192; }
  else if (b < 1536)  { in=i2; out=o2; K=256;   N=256; Kout=256;   tx=8;   lid=b-1472; }
  else if (b < 1600)  { in=i3; out=o3; K=256;   N=256; Kout=256;   tx=8;   lid=b-1536; }
  else                { in=i4; out=o4; K=10000; N=512; Kout=10240; tx=320; lid=b-1600; }
  int k0 = (lid % tx) * 32, n0 = (lid / tx) * 32;
  int txx = threadIdx.x & 31, tyy = threadIdx.x >> 5;
#pragma unroll
  for (int r = 0; r < 32; r += 8) {
    int k = k0 + tyy + r, n = n0 + txx;
    float v = (k < K) ? in[(size_t)k * N + n] : 0.f;
    tile[tyy + r][txx] = f2bf(v);
  }
  __syncthreads();
#pragma unroll
  for (int r = 0; r < 32; r += 8) {
    int n = n0 + tyy + r, k = k0 + txx;
    out[(size_t)n * Kout + k] = tile[txx][tyy + r];
  }
}

// ---------------------------------------------------- fp32 -> bf16 converts
__global__ void conv_graphx_k(const float* __restrict__ in, unsigned short* __restrict__ out) {
  size_t i = (size_t)(blockIdx.x * 256 + threadIdx.x) * 8;  // grid sized exactly
  f32x4 a = *(const f32x4*)(in + i);
  f32x4 b = *(const f32x4*)(in + i + 4);
  u16x8 o;
  o[0]=f2bf(a[0]); o[1]=f2bf(a[1]); o[2]=f2bf(a[2]); o[3]=f2bf(a[3]);
  o[4]=f2bf(b[0]); o[5]=f2bf(b[1]); o[6]=f2bf(b[2]); o[7]=f2bf(b[3]);
  *(u16x8*)(out + i) = o;
}

// data_x fp32 -> (optional) bf16 K-padded copy + fused segment-mean -> cat[:, :5000]
// grid (BG, 20): graph g, col chunk (256 cols of 5120)
__global__ __launch_bounds__(256) void conv_pool_k(const float* __restrict__ x,
                                                   unsigned short* __restrict__ xb,
                                                   unsigned short* __restrict__ cat,
                                                   const int* __restrict__ segs,
                                                   const int* __restrict__ sege) {
  int g = blockIdx.x;
  int c = blockIdx.y * 256 + threadIdx.x;  // < 5120
  int s = segs[g], e = sege[g];
  bool vc = c < RAWF;
  float sum = 0.f;
  if (xb) {
    int i = s;
    for (; i + 2 <= e; i += 2) {
      float v0 = 0.f, v1 = 0.f;
      if (vc) { v0 = x[(size_t)i * RAWF + c]; v1 = x[(size_t)(i + 1) * RAWF + c]; }
      xb[(size_t)i * KP + c] = f2bf(v0);
      xb[(size_t)(i + 1) * KP + c] = f2bf(v1);
      sum += v0 + v1;
    }
    for (; i < e; ++i) {
      float v = 0.f;
      if (vc) v = x[(size_t)i * RAWF + c];
      xb[(size_t)i * KP + c] = f2bf(v);
      sum += v;
    }
  } else if (vc) {
    float a0 = 0, a1 = 0, a2 = 0, a3 = 0;
    int i = s;
    for (; i + 4 <= e; i += 4) {
      a0 += x[(size_t)(i + 0) * RAWF + c];
      a1 += x[(size_t)(i + 1) * RAWF + c];
      a2 += x[(size_t)(i + 2) * RAWF + c];
      a3 += x[(size_t)(i + 3) * RAWF + c];
    }
    for (; i < e; ++i) a0 += x[(size_t)i * RAWF + c];
    sum = (a0 + a1) + (a2 + a3);
  }
  if (vc) cat[(size_t)g * CATK + c] = f2bf(sum / (float)(e - s));
}

// root rows -> cat[:, 5000:10240] (bf16, zero pad)
__global__ void root_cat_k(const float* __restrict__ data_x, const int* __restrict__ root,
                           unsigned short* __restrict__ cat) {
  int g = blockIdx.x;
  int c = blockIdx.y * 256 + threadIdx.x;
  if (c >= CATK - RAWF) return;  // covers 5000..10239
  unsigned short v = 0;
  if (c < RAWF) v = f2bf(data_x[(size_t)root[g] * RAWF + c]);
  cat[(size_t)g * CATK + RAWF + c] = v;
}

// ------------------------------------------------------------- MFMA GEMM
// C[M][N] (+)= A[M][K] @ Bt[N][K]bf16. 128x128x32 tile, 4 waves, register-
// prefetch pipeline (next tile's global loads issued before the MFMA block).
template <bool ABF16>
__global__ __launch_bounds__(256) void gemm_k(
    const void* __restrict__ Av, int Astride,
    const unsigned short* __restrict__ Bt, int Bstride,
    float* __restrict__ C, int M, int N, int Kreal, int kchunk, int atomic_out) {
  __shared__ unsigned short As[128 * 40];  // pad 32->40: 2-way bank alias only
  __shared__ unsigned short Bs[128 * 40];
  const int tid = threadIdx.x;
  const int lane = tid & 63, wave = tid >> 6;
  const int quad = lane >> 4, l16 = lane & 15;
  const int koff = quad * 8;
  const int bn = blockIdx.x * 128, bm = blockIdx.y * 128;
  const int wm = (wave >> 1) * 64, wn = (wave & 1) * 64;
  const int kbegin = blockIdx.z * kchunk;
  int kend = kbegin + kchunk; if (kend > Kreal) kend = Kreal;

  const int brow = tid >> 2, bcol = (tid & 3) * 8;   // bf16 16B loads, 2 rounds
  const int arow_f = tid >> 3, acol_f = (tid & 7) * 4;  // f32 16B loads, 4 rounds

  u16x8 pb[2];
  u16x8 pa_b[2];
  f32x4 pa_f[4];

  auto load_tile = [&](int k0) {
#pragma unroll
    for (int i = 0; i < 2; ++i) {
      int gk = k0 + bcol;
      bool ok = ABF16 ? true : (gk + 8 <= kend);  // N is always mult of 128
      u16x8 v = (u16x8)(unsigned short)0;
      if (ok) v = *(const u16x8*)(Bt + (size_t)(bn + i * 64 + brow) * Bstride + gk);
      pb[i] = v;
    }
    if (ABF16) {
      const unsigned short* A = (const unsigned short*)Av;
#pragma unroll
      for (int i = 0; i < 2; ++i) {
        int r = bm + i * 64 + brow;
        u16x8 v = (u16x8)(unsigned short)0;
        if (r < M) v = *(const u16x8*)(A + (size_t)r * Astride + k0 + bcol);
        pa_b[i] = v;
      }
    } else {
      const float* A = (const float*)Av;
#pragma unroll
      for (int i = 0; i < 4; ++i) {
        int r = bm + i * 32 + arow_f;
        int gk = k0 + acol_f;
        f32x4 v = (f32x4)0.f;
        if (r < M && gk + 4 <= kend) v = *(const f32x4*)(A + (size_t)r * Astride + gk);
        pa_f[i] = v;
      }
    }
  };
  auto store_tile = [&]() {
#pragma unroll
    for (int i = 0; i < 2; ++i)
      *(u16x8*)&Bs[(i * 64 + brow) * 40 + bcol] = pb[i];
    if (ABF16) {
#pragma unroll
      for (int i = 0; i < 2; ++i)
        *(u16x8*)&As[(i * 64 + brow) * 40 + bcol] = pa_b[i];
    } else {
#pragma unroll
      for (int i = 0; i < 4; ++i) {
        u16x4 h;
        h[0] = f2bf(pa_f[i][0]); h[1] = f2bf(pa_f[i][1]);
        h[2] = f2bf(pa_f[i][2]); h[3] = f2bf(pa_f[i][3]);
        *(u16x4*)&As[(i * 32 + arow_f) * 40 + acol_f] = h;
      }
    }
  };

  f32x4 acc[4][4] = {};
  load_tile(kbegin);
  for (int k0 = kbegin; k0 < kend; k0 += 32) {
    store_tile();
    __syncthreads();
    int k1 = k0 + 32;
    if (k1 < kend) load_tile(k1);  // prefetch: latency overlaps MFMA below
    u16x8 ar[4], br[4];
#pragma unroll
    for (int i = 0; i < 4; ++i) ar[i] = *(const u16x8*)&As[(wm + i * 16 + l16) * 40 + koff];
#pragma unroll
    for (int j = 0; j < 4; ++j) br[j] = *(const u16x8*)&Bs[(wn + j * 16 + l16) * 40 + koff];
#pragma unroll
    for (int i = 0; i < 4; ++i)
#pragma unroll
      for (int j = 0; j < 4; ++j)
        acc[i][j] = __builtin_amdgcn_mfma_f32_16x16x32_bf16(
            __builtin_bit_cast(bf16x8, ar[i]), __builtin_bit_cast(bf16x8, br[j]),
            acc[i][j], 0, 0, 0);
    __syncthreads();
  }
  // epilogue: D[row=quad*4+rr][col=l16] (m89/m91-verified mapping)
#pragma unroll
  for (int i = 0; i < 4; ++i)
#pragma unroll
    for (int rr = 0; rr < 4; ++rr) {
      int grow = bm + wm + i * 16 + quad * 4 + rr;
      if (grow >= M) continue;
#pragma unroll
      for (int j = 0; j < 4; ++j) {
        int gcol = bn + wn + j * 16 + l16;
        if (gcol >= N) continue;
        float v = acc[i][j][rr];
        if (atomic_out) atomicAdd(&C[(size_t)grow * N + gcol], v);
        else C[(size_t)grow * N + gcol] = v;
      }
    }
}

// ------------------------------------------------------------ GCN aggregate
// out[i] = relu(dinv[i]*(h[i]*dinv[i] + sum_in h[s]*dinv[s]) + bias), bf16 out
__global__ __launch_bounds__(256) void gcn_agg_k(
    const float* __restrict__ h, const int* __restrict__ rowptr,
    const int* __restrict__ col, const float* __restrict__ dinv,
    const float* __restrict__ bias, unsigned short* __restrict__ outb, int n) {
  int wave = threadIdx.x >> 6, lane = threadIdx.x & 63;
  int node = blockIdx.x * 4 + wave;
  if (node >= n) return;
  int f = lane * 4;
  float di = dinv[node];
  f32x4 acc = *(const f32x4*)(h + (size_t)node * HD + f) * di;  // self loop
  int beg = rowptr[node], end = rowptr[node + 1];
  int e = beg;
  for (; e + 4 <= end; e += 4) {
    int s0 = col[e], s1 = col[e + 1], s2 = col[e + 2], s3 = col[e + 3];
    float w0 = dinv[s0], w1 = dinv[s1], w2 = dinv[s2], w3 = dinv[s3];
    f32x4 h0 = *(const f32x4*)(h + (size_t)s0 * HD + f);
    f32x4 h1 = *(const f32x4*)(h + (size_t)s1 * HD + f);
    f32x4 h2 = *(const f32x4*)(h + (size_t)s2 * HD + f);
    f32x4 h3 = *(const f32x4*)(h + (size_t)s3 * HD + f);
    acc += h0 * w0; acc += h1 * w1; acc += h2 * w2; acc += h3 * w3;
  }
  for (; e < end; ++e) {
    int s = col[e];
    acc += *(const f32x4*)(h + (size_t)s * HD + f) * dinv[s];
  }
  f32x4 b = *(const f32x4*)(bias + f);
  acc = acc * di + b;
  u16x4 o;
#pragma unroll
  for (int q = 0; q < 4; ++q) o[q] = f2bf(fmaxf(acc[q], 0.f));
  *(u16x4*)(outb + (size_t)node * HD + f) = o;
}

// -------------------------------------------------------------- pooling (bf16 src, HD cols)
__global__ __launch_bounds__(256) void seg_pool_bf16_k(const unsigned short* __restrict__ src,
                                                       const int* __restrict__ segs,
                                                       const int* __restrict__ sege,
                                                       float* __restrict__ dst, int dstride,
                                                       int doff, int mode) {
  int g = blockIdx.x, f = threadIdx.x;
  int s = segs[g], e = sege[g];
  float a0, a1, a2, a3;
  if (mode == 1) { a0 = a1 = a2 = a3 = -INFINITY; } else { a0 = a1 = a2 = a3 = 0.f; }
  int i = s;
  for (; i + 4 <= e; i += 4) {
    float v0 = bf2f(src[(size_t)(i + 0) * HD + f]);
    float v1 = bf2f(src[(size_t)(i + 1) * HD + f]);
    float v2 = bf2f(src[(size_t)(i + 2) * HD + f]);
    float v3 = bf2f(src[(size_t)(i + 3) * HD + f]);
    if (mode == 1) { a0 = fmaxf(a0, v0); a1 = fmaxf(a1, v1); a2 = fmaxf(a2, v2); a3 = fmaxf(a3, v3); }
    else           { a0 += v0; a1 += v1; a2 += v2; a3 += v3; }
  }
  for (; i < e; ++i) {
    float v = bf2f(src[(size_t)i * HD + f]);
    if (mode == 1) a0 = fmaxf(a0, v); else a0 += v;
  }
  float acc;
  if (mode == 1) acc = fmaxf(fmaxf(a0, a1), fmaxf(a2, a3));
  else {
    acc = (a0 + a1) + (a2 + a3);
    acc /= (float)((e - s) > 0 ? (e - s) : 1);
  }
  dst[(size_t)g * dstride + doff + f] = acc;
}

// ----------------------------------------------------------- small epilogues
__global__ void bias_prelu_k(const float* __restrict__ in, const float* __restrict__ bias,
                             const float* __restrict__ pa, float* __restrict__ out,
                             int total, int cols) {
  int i = blockIdx.x * 256 + threadIdx.x;
  if (i >= total) return;
  float v = in[i] + bias[i % cols];
  float a = *pa;
  out[i] = (v >= 0.f) ? v : a * v;
}

__global__ __launch_bounds__(256) void gemm_e_k(const float* __restrict__ t1,
                                                const float* __restrict__ Wl2,
                                                const float* __restrict__ bl2,
                                                const float* __restrict__ pa,
                                                float* __restrict__ pools) {
  int b = blockIdx.x, n = threadIdx.x;
  float acc = 0.f;
  for (int k = 0; k < 512; ++k) acc = fmaf(t1[b * 512 + k], Wl2[k * 256 + n], acc);
  acc += bl2[n];
  float a = *pa;
  acc = (acc >= 0.f) ? acc : a * acc;
  pools[(size_t)b * 1280 + 768 + n] = acc;
}

__global__ __launch_bounds__(256) void final_k(const float* __restrict__ pools,
                                               const float* __restrict__ W5,
                                               const float* __restrict__ b5,
                                               float* __restrict__ out) {
  __shared__ float red[256][4];
  int b = blockIdx.x, t = threadIdx.x;
  float a0 = 0, a1 = 0, a2 = 0, a3 = 0;
  for (int i = t; i < 1280; i += 256) {
    float p = pools[(size_t)b * 1280 + i];
    a0 = fmaf(p, W5[i * 4 + 0], a0);
    a1 = fmaf(p, W5[i * 4 + 1], a1);
    a2 = fmaf(p, W5[i * 4 + 2], a2);
    a3 = fmaf(p, W5[i * 4 + 3], a3);
  }
  red[t][0] = a0; red[t][1] = a1; red[t][2] = a2; red[t][3] = a3;
  __syncthreads();
  for (int off = 128; off >= 1; off >>= 1) {
    if (t < off)
      for (int c = 0; c < 4; ++c) red[t][c] += red[t + off][c];
    __syncthreads();
  }
  if (t == 0) {
    float z[4];
    for (int c = 0; c < 4; ++c) z[c] = red[0][c] + b5[c];
    float m = fmaxf(fmaxf(z[0], z[1]), fmaxf(z[2], z[3]));
    float s = 0.f;
    for (int c = 0; c < 4; ++c) s += expf(z[c] - m);
    float lse = logf(s);
    for (int c = 0; c < 4; ++c) out[b * 4 + c] = z[c] - m - lse;
  }
}

// ================================================================ launcher
extern "C" void kernel_launch(void* const* d_in, const int* in_sizes, int n_in,
                              void* d_out, int out_size, void* d_ws, size_t ws_size,
                              hipStream_t stream) {
  const float* graph_x = (const float*)d_in[0];
  const float* data_x  = (const float*)d_in[2];
  const int*   ei      = (const int*)d_in[3];
  const int*   rei     = (const int*)d_in[4];
  const int*   batch   = (const int*)d_in[5];
  const int*   rooti   = (const int*)d_in[7];
  const float* W1  = (const float*)d_in[8];   const float* b1  = (const float*)d_in[9];
  const float* Wc0 = (const float*)d_in[10];  const float* bc0 = (const float*)d_in[11];
  const float* Wc1 = (const float*)d_in[12];  const float* bc1 = (const float*)d_in[13];
  const float* Wc2 = (const float*)d_in[14];  const float* bc2 = (const float*)d_in[15];
  const float* Wl1 = (const float*)d_in[16];  const float* bl1 = (const float*)d_in[17];
  const float* Wl2 = (const float*)d_in[18];  const float* bl2 = (const float*)d_in[19];
  const float* pa  = (const float*)d_in[20];
  const float* W5  = (const float*)d_in[21];  const float* b5  = (const float*)d_in[22];
  float* out = (float*)d_out;

  char* ws = (char*)d_ws;
  size_t off = 0;
  auto take = [&](size_t bytes) -> void* {
    void* p = ws + off;
    off += (bytes + 255) & ~(size_t)255;
    return p;
  };
  const int NB = ceil_div(NN, 1024);  // 20

  int *deg1, *deg2, *rp1, *rp2, *cur1, *cur2, *col1, *col2, *excl, *bsum, *boff, *segs, *sege;
  float *dv1, *dv2, *hA, *Cd, *t1, *pools;
  unsigned short *W1t, *Wc0t, *Wc1t, *Wc2t, *Wl1t, *gxb, *catb, *hBb, *Axb;

  auto alloc_all = [&](bool withAxb) {
    off = 0;
    deg1 = (int*)take(NN * 4);   deg2 = (int*)take(NN * 4);   // adjacent: one memset
    rp1  = (int*)take((NN + 1) * 4); rp2 = (int*)take((NN + 1) * 4);
    cur1 = (int*)take(NN * 4);   cur2 = (int*)take(NN * 4);
    col1 = (int*)take(EE * 4);   col2 = (int*)take(EE * 4);
    dv1  = (float*)take(NN * 4); dv2  = (float*)take(NN * 4);
    excl = (int*)take((size_t)2 * NN * 4);
    bsum = (int*)take(2 * NB * 4); boff = (int*)take(2 * NB * 4);
    segs = (int*)take(BG * 4);   sege = (int*)take(BG * 4);
    W1t  = (unsigned short*)take((size_t)HD * FIN * 2);
    Wc0t = (unsigned short*)take((size_t)HD * KP * 2);
    Wc1t = (unsigned short*)take((size_t)HD * HD * 2);
    Wc2t = (unsigned short*)take((size_t)HD * HD * 2);
    Wl1t = (unsigned short*)take((size_t)512 * CATK * 2);
    gxb  = (unsigned short*)take((size_t)NN * FIN * 2);
    catb = (unsigned short*)take((size_t)BG * CATK * 2);
    Axb  = withAxb ? (unsigned short*)take((size_t)NN * KP * 2) : nullptr;
    hA   = (float*)take((size_t)NN * HD * 4);
    hBb  = (unsigned short*)take((size_t)NN * HD * 2);
    Cd   = (float*)take((size_t)BG * 512 * 4);
    t1   = (float*)take((size_t)BG * 512 * 4);
    pools = (float*)take((size_t)BG * 1280 * 4);
  };
  alloc_all(true);
  if (off > ws_size) alloc_all(false);
  const bool pathA = (Axb != nullptr);

  // ---- zero-init
  hipMemsetAsync(deg1, 0, (size_t)2 * ((NN * 4 + 255) & ~255), stream);  // deg1+deg2
  hipMemsetAsync(Cd, 0, (size_t)BG * 512 * 4, stream);

  // ---- CSR build (both graphs)
  count_deg2_k<<<ceil_div(2 * EE, 256), 256, 0, stream>>>(ei, rei, deg1, deg2);
  scan_local_k<<<dim3(NB, 2), 1024, 0, stream>>>(deg1, deg2, excl, bsum, NB);
  scan_tops_k<<<1, 64, 0, stream>>>(bsum, boff, rp1 + NN, rp2 + NN, NB);
  scan_add_k<<<dim3(NB, 2), 1024, 0, stream>>>(excl, boff, deg1, deg2, rp1, rp2,
                                               cur1, cur2, dv1, dv2, NB);
  scatter_k<<<dim3(ceil_div(EE, 256), 2), 256, 0, stream>>>(ei, rei, cur1, cur2, col1, col2);
  segbounds_k<<<ceil_div(NN, 256), 256, 0, stream>>>(batch, segs, sege, NN);

  // ---- weight transposes (batched, 6720 blocks)
  trans_k<<<6720, 256, 0, stream>>>(W1, W1t, Wc0, Wc0t, Wc1, Wc1t, Wc2, Wc2t, Wl1, Wl1t);

  // ---- input converts (+ fused segment-mean -> cat left half)
  conv_graphx_k<<<(NN * FIN) / (256 * 8), 256, 0, stream>>>(graph_x, gxb);
  conv_pool_k<<<dim3(BG, KP / 256), 256, 0, stream>>>(data_x, Axb, catb, segs, sege);
  root_cat_k<<<dim3(BG, ceil_div(CATK - RAWF, 256)), 256, 0, stream>>>(data_x, rooti, catb);

  int mt = ceil_div(NN, 128);  // 157

  // ---- branch 1: GCN(graph_x) -> relu -> segment_max
  hipMemsetAsync(hA, 0, (size_t)NN * HD * 4, stream);
  gemm_k<true><<<dim3(2, mt, 3), 256, 0, stream>>>(gxb, FIN, W1t, FIN, hA, NN, HD, FIN, 256, 1);
  gcn_agg_k<<<ceil_div(NN, 4), 256, 0, stream>>>(hA, rp1, col1, dv1, b1, hBb, NN);
  seg_pool_bf16_k<<<BG, 256, 0, stream>>>(hBb, segs, sege, pools, 1280, 1024, 1);

  // ---- branch 3 layer 0 (the big one)
  hipMemsetAsync(hA, 0, (size_t)NN * HD * 4, stream);
  if (pathA)
    gemm_k<true><<<dim3(2, mt, 4), 256, 0, stream>>>(Axb, KP, Wc0t, KP, hA, NN, HD, KP, 1280, 1);
  else
    gemm_k<false><<<dim3(2, mt, 4), 256, 0, stream>>>(data_x, RAWF, Wc0t, KP, hA, NN, HD, RAWF, 1256, 1);
  gcn_agg_k<<<ceil_div(NN, 4), 256, 0, stream>>>(hA, rp2, col2, dv2, bc0, hBb, NN);
  seg_pool_bf16_k<<<BG, 256, 0, stream>>>(hBb, segs, sege, pools, 1280, 0, 0);

  // ---- branch 3 layer 1
  hipMemsetAsync(hA, 0, (size_t)NN * HD * 4, stream);
  gemm_k<true><<<dim3(2, mt, 2), 256, 0, stream>>>(hBb, HD, Wc1t, HD, hA, NN, HD, HD, 128, 1);
  gcn_agg_k<<<ceil_div(NN, 4), 256, 0, stream>>>(hA, rp2, col2, dv2, bc1, hBb, NN);
  seg_pool_bf16_k<<<BG, 256, 0, stream>>>(hBb, segs, sege, pools, 1280, 256, 0);

  // ---- branch 3 layer 2
  hipMemsetAsync(hA, 0, (size_t)NN * HD * 4, stream);
  gemm_k<true><<<dim3(2, mt, 2), 256, 0, stream>>>(hBb, HD, Wc2t, HD, hA, NN, HD, HD, 128, 1);
  gcn_agg_k<<<ceil_div(NN, 4), 256, 0, stream>>>(hA, rp2, col2, dv2, bc2, hBb, NN);
  seg_pool_bf16_k<<<BG, 256, 0, stream>>>(hBb, segs, sege, pools, 1280, 512, 0);

  // ---- branch 2: cat @ Wl1 (split-K 32) -> prelu -> @ Wl2 -> prelu
  gemm_k<true><<<dim3(4, 1, 32), 256, 0, stream>>>(catb, CATK, Wl1t, CATK, Cd, BG, 512, CATK, 320, 1);
  bias_prelu_k<<<ceil_div(BG * 512, 256), 256, 0, stream>>>(Cd, bl1, pa, t1, BG * 512, 512);
  gemm_e_k<<<BG, 256, 0, stream>>>(t1, Wl2, bl2, pa, pools);

  // ---- final concat @ W5 + log_softmax
  final_k<<<BG, 256, 0, stream>>>(pools, W5, b5, out);
}